// Round 23
// baseline (1095.919 us; speedup 1.0000x reference)
//
#include <hip/hip_runtime.h>
#include <cstdint>
#include <cstddef>

#define DEV static __device__ __forceinline__

typedef __attribute__((ext_vector_type(8))) short bf16x8;
typedef __attribute__((ext_vector_type(4))) float f32x4;
typedef __attribute__((ext_vector_type(16))) float f32x16;

#define T_SEQ 4096
#define CDIM  768
#define NH    12
#define HD    64
#define NBH   24            // B * NH
#define M_ROWS 8192         // B * T

// ---- workspace layout (bytes) ----
#define OFF_XB   0ull
#define OFF_WAT  (OFF_XB  + (size_t)M_ROWS * CDIM * 2)       // xb: [8192][768] bf16
#define OFF_WPT  (OFF_WAT + (size_t)(3*CDIM) * CDIM * 2)     // WaT: [2304][768] bf16
#define OFF_Q    (OFF_WPT + (size_t)CDIM * CDIM * 2)         // WpT: [768][768] bf16
#define OFF_K    (OFF_Q   + (size_t)NBH * T_SEQ * HD * 2)    // Q: [24][4096][64] bf16 (pre-scaled by log2e/8)
#define OFF_VT   (OFF_K   + (size_t)NBH * T_SEQ * HD * 2)    // K: [24][4096][64] bf16
#define OFF_O    (OFF_VT  + (size_t)NBH * HD * T_SEQ * 2)    // Vt: [24][64][4096] bf16 (key cols bit2<->bit3 permuted)
#define OFF_P    (OFF_O   + (size_t)M_ROWS * CDIM * 2)       // O (combined): [8192][768] bf16
#define OFF_L    (OFF_P   + 2ull * M_ROWS * CDIM * 2)        // Op partials: [2][8192][768] bf16
// Lp partials: [2][24][4096] f32

DEV unsigned short f2bf(float f) {            // RTNE f32 -> bf16
  unsigned u = __builtin_bit_cast(unsigned, f);
  u += 0x7FFFu + ((u >> 16) & 1u);
  return (unsigned short)(u >> 16);
}

DEV void gld_lds16(const void* g, void* l) {  // async global->LDS, 16B/lane, dest = wave-uniform base + lane*16
  __builtin_amdgcn_global_load_lds(
      (const __attribute__((address_space(1))) void*)g,
      (__attribute__((address_space(3))) void*)l, 16, 0, 0);
}

// Atomic 8x cvt_pk blob: all cvts contiguous (no MFMA can be scheduled between them)
// + s_nop 3 tail so every output has >=4 wait states before any consuming MFMA.
DEV void cvt8(const f32x16& s, unsigned* w) {
  asm("v_cvt_pk_bf16_f32 %0, %8, %9\n\t"
      "v_cvt_pk_bf16_f32 %1, %10, %11\n\t"
      "v_cvt_pk_bf16_f32 %2, %12, %13\n\t"
      "v_cvt_pk_bf16_f32 %3, %14, %15\n\t"
      "v_cvt_pk_bf16_f32 %4, %16, %17\n\t"
      "v_cvt_pk_bf16_f32 %5, %18, %19\n\t"
      "v_cvt_pk_bf16_f32 %6, %20, %21\n\t"
      "v_cvt_pk_bf16_f32 %7, %22, %23\n\t"
      "s_nop 3"
      : "=&v"(w[0]), "=&v"(w[1]), "=&v"(w[2]), "=&v"(w[3]),
        "=&v"(w[4]), "=&v"(w[5]), "=&v"(w[6]), "=&v"(w[7])
      : "v"(s[0]), "v"(s[1]), "v"(s[2]), "v"(s[3]),
        "v"(s[4]), "v"(s[5]), "v"(s[6]), "v"(s[7]),
        "v"(s[8]), "v"(s[9]), "v"(s[10]), "v"(s[11]),
        "v"(s[12]), "v"(s[13]), "v"(s[14]), "v"(s[15]));
}

// ---------------- kernel 1: cast x f32 -> bf16 ----------------
__global__ __launch_bounds__(256) void k_conv(const float* __restrict__ in,
                                              unsigned short* __restrict__ out) {
  int i = blockIdx.x * 256 + threadIdx.x;
  const float4* p = (const float4*)in;
  float4 a = p[i * 2], b = p[i * 2 + 1];
  uint4 o;
  o.x = (unsigned)f2bf(a.x) | ((unsigned)f2bf(a.y) << 16);
  o.y = (unsigned)f2bf(a.z) | ((unsigned)f2bf(a.w) << 16);
  o.z = (unsigned)f2bf(b.x) | ((unsigned)f2bf(b.y) << 16);
  o.w = (unsigned)f2bf(b.z) | ((unsigned)f2bf(b.w) << 16);
  ((uint4*)out)[i] = o;
}

// ---------------- kernel 2: transpose [R][C] f32 -> [C][R] bf16 ----------------
__global__ __launch_bounds__(256) void k_transpose(const float* __restrict__ in,
                                                   unsigned short* __restrict__ out,
                                                   int R, int C) {
  __shared__ float tile[64][65];
  int c0 = blockIdx.x * 64, r0 = blockIdx.y * 64;
  int tid = threadIdx.x;
  for (int i = tid; i < 4096; i += 256) {
    int r = i >> 6, c = i & 63;
    tile[r][c] = in[(size_t)(r0 + r) * C + c0 + c];
  }
  __syncthreads();
  for (int i = tid; i < 4096; i += 256) {
    int c = i >> 6, r = i & 63;
    out[(size_t)(c0 + c) * R + r0 + r] = f2bf(tile[r][c]);
  }
}

// ---------------- kernel 3: QKV GEMM  [8192][768] @ [768][2304] (+bias) ----------------
// Epilogue staged through LDS (reusing the 32 KB staging buffer) so all Q/K/Vt stores
// are coalesced b128 (r22: -11.5 us vs scalar scatter).
__global__ __launch_bounds__(256) void k_qkv(const unsigned short* __restrict__ A,
                                             const unsigned short* __restrict__ Bt,
                                             const float* __restrict__ bias,
                                             unsigned short* __restrict__ Qo,
                                             unsigned short* __restrict__ Ko,
                                             unsigned short* __restrict__ Vt) {
  __shared__ short LDSBUF[2][128 * 64];   // As | Bs; reused as 128x128 bf16 in the epilogue
  short* As = &LDSBUF[0][0];
  short* Bs = &LDSBUF[1][0];
  const int tid = threadIdx.x;
  const int wave = tid >> 6, lane = tid & 63;
  const int wr = wave >> 1, wc = wave & 1;
  // XCD-aware swizzle (m204, 1152 = 8*144)
  const int lin = blockIdx.y * 18 + blockIdx.x;
  const int wg = (lin & 7) * 144 + (lin >> 3);
  const int m0 = (wg / 18) * 128, n0 = (wg % 18) * 128;

  f32x4 acc[4][4] = {};

#pragma unroll 1
  for (int k0 = 0; k0 < 768; k0 += 64) {
#pragma unroll
    for (int it = 0; it < 4; ++it) {
      int chunk = wave * 4 + it;
      int slot = chunk * 64 + lane;
      int row = slot >> 3, j = slot & 7;
      int kcol = k0 + ((j ^ (row & 7)) << 3);
      gld_lds16(A  + (size_t)(m0 + row) * 768 + kcol, &As[chunk * 512]);
      gld_lds16(Bt + (size_t)(n0 + row) * 768 + kcol, &Bs[chunk * 512]);
    }
    __syncthreads();
#pragma unroll
    for (int kk = 0; kk < 2; ++kk) {
      bf16x8 af[4], bfr[4];
      int cbl = kk * 4 + (lane >> 4);
#pragma unroll
      for (int mi = 0; mi < 4; ++mi) {
        int row = wr * 64 + mi * 16 + (lane & 15);
        af[mi] = *(const bf16x8*)&As[(row * 8 + (cbl ^ (row & 7))) * 8];
      }
#pragma unroll
      for (int ni = 0; ni < 4; ++ni) {
        int row = wc * 64 + ni * 16 + (lane & 15);
        bfr[ni] = *(const bf16x8*)&Bs[(row * 8 + (cbl ^ (row & 7))) * 8];
      }
#pragma unroll
      for (int mi = 0; mi < 4; ++mi)
#pragma unroll
        for (int ni = 0; ni < 4; ++ni)
          acc[mi][ni] = __builtin_amdgcn_mfma_f32_16x16x32_bf16(af[mi], bfr[ni], acc[mi][ni], 0, 0, 0);
    }
    __syncthreads();
  }

  // ---- epilogue via LDS: coalesced stores ----
  __syncthreads();                       // done with As/Bs staging contents
  char* T = (char*)&LDSBUF[0][0];        // 128 rows x 256 B (bf16 x 128), XOR-swizzled chunks
  const int which = n0 / 768;
  const int hbase = (n0 - which * 768) >> 6;   // first of the 2 heads in this 128-col tile
  const int b = m0 >> 12, t0 = m0 & 4095;

  if (which < 2) {
    const float qs = (which == 0) ? 0.18033688011112042f : 1.0f;  // Q pre-scaled by log2e/8
#pragma unroll
    for (int ni = 0; ni < 4; ++ni) {
      int colL = wc * 64 + ni * 16 + (lane & 15);
      float bi = bias[n0 + colL];
#pragma unroll
      for (int mi = 0; mi < 4; ++mi) {
#pragma unroll
        for (int r = 0; r < 4; ++r) {
          int mL = wr * 64 + mi * 16 + ((lane >> 4) << 2) + r;
          *(unsigned short*)(T + mL * 256 + ((colL * 2) ^ ((mL & 7) << 4))) =
              f2bf((acc[mi][ni][r] + bi) * qs);
        }
      }
    }
    __syncthreads();
    unsigned short* OUT = (which == 0) ? Qo : Ko;
#pragma unroll
    for (int p = 0; p < 8; ++p) {
      int row = p * 16 + (tid >> 4);     // t_local
      int c = tid & 15;                  // 8-elem chunk of the 128 cols
      bf16x8 v = *(const bf16x8*)(T + row * 256 + (((c ^ (row & 7)) << 4)));
      int h = hbase + (c >> 3), d0 = (c & 7) * 8;
      size_t bh = (size_t)(b * NH + h);
      *(bf16x8*)&OUT[bh * (size_t)(T_SEQ * HD) + (size_t)(t0 + row) * HD + d0] = v;
    }
  } else {
    // Vt: stage TRANSPOSED with the bit2<->3 t-permute, store rows of 128 consecutive t
#pragma unroll
    for (int ni = 0; ni < 4; ++ni) {
      int colL = wc * 64 + ni * 16 + (lane & 15);
      float bi = bias[n0 + colL];
#pragma unroll
      for (int mi = 0; mi < 4; ++mi) {
#pragma unroll
        for (int r = 0; r < 4; ++r) {
          int mL = wr * 64 + mi * 16 + ((lane >> 4) << 2) + r;
          int mp = (mL & ~12) | ((mL & 4) << 1) | ((mL & 8) >> 1);   // t-permute (local bits)
          *(unsigned short*)(T + colL * 256 + ((mp * 2) ^ ((colL & 7) << 4))) =
              f2bf(acc[mi][ni][r] + bi);
        }
      }
    }
    __syncthreads();
#pragma unroll
    for (int p = 0; p < 8; ++p) {
      int row = p * 16 + (tid >> 4);     // colLocal = (head,d)
      int c = tid & 15;                  // 8-elem chunk of the 128 t
      bf16x8 v = *(const bf16x8*)(T + row * 256 + (((c ^ (row & 7)) << 4)));
      int h = hbase + (row >> 6), d = row & 63;
      size_t bh = (size_t)(b * NH + h);
      *(bf16x8*)&Vt[bh * (size_t)(T_SEQ * HD) + (size_t)d * T_SEQ + t0 + c * 8] = v;
    }
  }
}

// ---------------- kernel 4: flash attention (4 waves x 64 q/wave, K-SPLIT=2) ----------------
// grid (16 qtiles of 256 q, 24 bh, 2 ks), XCD-swizzled. Each wave owns 64 queries
// (2 Q-slices); K/V LDS reads are CSE'd across slices (r18: conflicts halved).
// __launch_bounds__(256,4): allocator settled at 116 VGPR under cap 256 (r21), which
// fits the 128-VGPR cap of 4 waves/SIMD -> all 3 grid-blocks/CU co-resident
// (r21/r22 occupancy was 18% with the (256,2) residency cap). LDS 32KB x 4 = 128KB ok.
__global__ __launch_bounds__(256, 4) void k_attn(const unsigned short* __restrict__ Q,
                                                 const unsigned short* __restrict__ K,
                                                 const unsigned short* __restrict__ Vt,
                                                 unsigned short* __restrict__ Op,
                                                 float* __restrict__ Lp) {
  __shared__ char ldsb[2][16384];   // [buf][ K tile 8 KiB | Vt tile 8 KiB ], XOR-swizzled
  const int tid = threadIdx.x, wave = tid >> 6, lane = tid & 63;
  const int hi = lane >> 5, l31 = lane & 31;
  // XCD-aware swizzle (m204, 384 = 8*48): XCD x owns bh [3x, 3x+3)
  const int lin = blockIdx.y * 16 + blockIdx.x;
  const int wg = (lin & 7) * 48 + (lin >> 3);
  const int qt = wg & 15, bh = wg >> 4, ks = blockIdx.z;
  const int b = bh / NH, h = bh % NH;
  const size_t base = (size_t)bh * T_SEQ * HD;
  const int q0 = qt * 256 + wave * 64;     // this wave's 64 queries: slices +0..31, +32..63

  // Q fragments (B-operand) per slice: col=q=l31, k(d) = 16t + 8*hi + j
  bf16x8 aq[2][4];
#pragma unroll
  for (int qf = 0; qf < 2; ++qf)
#pragma unroll
    for (int t = 0; t < 4; ++t)
      aq[qf][t] = *(const bf16x8*)&Q[base + (size_t)(q0 + qf * 32 + l31) * HD + t * 16 + hi * 8];

  // hoisted LDS byte offsets (lane-only)
  int koff[4];
#pragma unroll
  for (int t = 0; t < 4; ++t)
    koff[t] = l31 * 128 + ((((t << 1) | hi) ^ (l31 & 7)) << 4);
  int voff[2][2];
#pragma unroll
  for (int kb = 0; kb < 2; ++kb)
#pragma unroll
    for (int kss = 0; kss < 2; ++kss)
      voff[kb][kss] = ((((kb << 2) | (kss << 1) | hi) ^ (l31 & 7)) << 4) + l31 * 128;

  f32x16 oacc[2][2] = {};    // [qf][db]
  float lsum[2] = {0.f, 0.f};

  auto STAGE = [&](int bufi, int k0) {
#pragma unroll
    for (int it = 0; it < 2; ++it) {
      int chunk = wave * 2 + it;             // 4 waves x 2 = chunks 0..7
      int slot = chunk * 64 + lane;
      int row = slot >> 3, j = slot & 7;
      int ce = ((j ^ (row & 7)) << 3);       // pre-swizzled source column (elements)
      gld_lds16(K  + base + (size_t)(k0 + row) * HD + ce, ldsb[bufi] + chunk * 1024);
      gld_lds16(Vt + base + (size_t)row * T_SEQ + k0 + ce, ldsb[bufi] + 8192 + chunk * 1024);
    }
  };

  const int kt0 = ks * 32, ktEnd = kt0 + 32;
  STAGE(0, kt0 * 64);
  __syncthreads();

  int buf = 0;
#pragma unroll 1
  for (int kt = kt0; kt < ktEnd; ++kt) {
    if (kt + 1 < ktEnd) STAGE(buf ^ 1, (kt + 1) * 64);
    const char* Lq = ldsb[buf];
    const char* Vp = Lq + 8192;

#pragma unroll
    for (int qf = 0; qf < 2; ++qf) {
      // ---- QK0: S^T half 0 (keys kb=0)
      f32x16 s0 = {};
#pragma unroll
      for (int t = 0; t < 4; ++t) {
        bf16x8 kf = *(const bf16x8*)(Lq + koff[t]);
        s0 = __builtin_amdgcn_mfma_f32_32x32x16_bf16(kf, aq[qf][t], s0, 0, 0, 0);
      }
      // ---- exp2 + l-tree + cvt 0
#pragma unroll
      for (int r = 0; r < 16; ++r) s0[r] = __builtin_amdgcn_exp2f(s0[r]);
      {
        float a8[8];
#pragma unroll
        for (int i = 0; i < 8; ++i) a8[i] = s0[2 * i] + s0[2 * i + 1];
        float a4a = a8[0] + a8[1], a4b = a8[2] + a8[3], a4c = a8[4] + a8[5], a4d = a8[6] + a8[7];
        lsum[qf] += (a4a + a4b) + (a4c + a4d);
      }
      unsigned w0[8];
      cvt8(s0, w0);
      union { unsigned u[4]; bf16x8 v; } pf00, pf01;
      pf00.u[0] = w0[0]; pf00.u[1] = w0[1]; pf00.u[2] = w0[2]; pf00.u[3] = w0[3];
      pf01.u[0] = w0[4]; pf01.u[1] = w0[5]; pf01.u[2] = w0[6]; pf01.u[3] = w0[7];

      // ---- QK1: S^T half 1 (keys kb=1)
      f32x16 s1 = {};
#pragma unroll
      for (int t = 0; t < 4; ++t) {
        bf16x8 kf = *(const bf16x8*)(Lq + 4096 + koff[t]);
        s1 = __builtin_amdgcn_mfma_f32_32x32x16_bf16(kf, aq[qf][t], s1, 0, 0, 0);
      }

      // ---- PV0 (matrix pipe) — overlaps exp2/cvt 1 below
      {
        bf16x8 v0 = *(const bf16x8*)(Vp + voff[0][0]);
        bf16x8 v1 = *(const bf16x8*)(Vp + voff[0][1]);
        bf16x8 u0 = *(const bf16x8*)(Vp + 4096 + voff[0][0]);
        bf16x8 u1 = *(const bf16x8*)(Vp + 4096 + voff[0][1]);
        oacc[qf][0] = __builtin_amdgcn_mfma_f32_32x32x16_bf16(pf00.v, v0, oacc[qf][0], 0, 0, 0);
        oacc[qf][0] = __builtin_amdgcn_mfma_f32_32x32x16_bf16(pf01.v, v1, oacc[qf][0], 0, 0, 0);
        oacc[qf][1] = __builtin_amdgcn_mfma_f32_32x32x16_bf16(pf00.v, u0, oacc[qf][1], 0, 0, 0);
        oacc[qf][1] = __builtin_amdgcn_mfma_f32_32x32x16_bf16(pf01.v, u1, oacc[qf][1], 0, 0, 0);
      }

      // ---- exp2 + l-tree + cvt 1
#pragma unroll
      for (int r = 0; r < 16; ++r) s1[r] = __builtin_amdgcn_exp2f(s1[r]);
      {
        float a8[8];
#pragma unroll
        for (int i = 0; i < 8; ++i) a8[i] = s1[2 * i] + s1[2 * i + 1];
        float a4a = a8[0] + a8[1], a4b = a8[2] + a8[3], a4c = a8[4] + a8[5], a4d = a8[6] + a8[7];
        lsum[qf] += (a4a + a4b) + (a4c + a4d);
      }
      unsigned w1[8];
      cvt8(s1, w1);
      union { unsigned u[4]; bf16x8 v; } pf10, pf11;
      pf10.u[0] = w1[0]; pf10.u[1] = w1[1]; pf10.u[2] = w1[2]; pf10.u[3] = w1[3];
      pf11.u[0] = w1[4]; pf11.u[1] = w1[5]; pf11.u[2] = w1[6]; pf11.u[3] = w1[7];

      // ---- PV1
      {
        bf16x8 v0 = *(const bf16x8*)(Vp + voff[1][0]);
        bf16x8 v1 = *(const bf16x8*)(Vp + voff[1][1]);
        bf16x8 u0 = *(const bf16x8*)(Vp + 4096 + voff[1][0]);
        bf16x8 u1 = *(const bf16x8*)(Vp + 4096 + voff[1][1]);
        oacc[qf][0] = __builtin_amdgcn_mfma_f32_32x32x16_bf16(pf10.v, v0, oacc[qf][0], 0, 0, 0);
        oacc[qf][0] = __builtin_amdgcn_mfma_f32_32x32x16_bf16(pf11.v, v1, oacc[qf][0], 0, 0, 0);
        oacc[qf][1] = __builtin_amdgcn_mfma_f32_32x32x16_bf16(pf10.v, u0, oacc[qf][1], 0, 0, 0);
        oacc[qf][1] = __builtin_amdgcn_mfma_f32_32x32x16_bf16(pf11.v, u1, oacc[qf][1], 0, 0, 0);
      }
    }

    __syncthreads();
    buf ^= 1;
  }

  // epilogue: UNNORMALIZED partials. Op[ks][b*T+t][h*64+d] bf16; Lp[ks][bh][t] f32.
  // Combine hi-halves first, then lane l31 (hi==0) writes the full l for its query.
  unsigned short* OpS = Op + (size_t)ks * M_ROWS * CDIM;
  float* LpS = Lp + (size_t)ks * NBH * T_SEQ;
#pragma unroll
  for (int qf = 0; qf < 2; ++qf) {
    float l = lsum[qf];
    l += __shfl_xor(l, 32, 64);
    if (hi == 0) LpS[(size_t)bh * T_SEQ + (q0 + qf * 32 + l31)] = l;
#pragma unroll
    for (int r = 0; r < 16; ++r) {
      int t = q0 + qf * 32 + ((r & 3) + 8 * (r >> 2)) + 4 * hi;
      size_t rowb = (size_t)(b * T_SEQ + t) * CDIM + h * 64;
      OpS[rowb + l31]      = f2bf(oacc[qf][0][r]);
      OpS[rowb + 32 + l31] = f2bf(oacc[qf][1][r]);
    }
  }
}

// ---------------- kernel 4b: combine K-split partials  O = (O0+O1)/(l0+l1) ----------------
__global__ __launch_bounds__(256) void k_combine(const unsigned short* __restrict__ Op,
                                                 const float* __restrict__ Lp,
                                                 unsigned short* __restrict__ Ob) {
  int i = blockIdx.x * 256 + threadIdx.x;      // one 8-elem chunk; 8192*768/8/256 = 3072 blocks
  size_t e = (size_t)i * 8;
  int c = (int)(e % CDIM);
  int bt = (int)(e / CDIM);
  int t = bt & 4095, b = bt >> 12;
  int h = c >> 6;
  size_t li = (size_t)(b * NH + h) * T_SEQ + t;
  float inv = 1.0f / (Lp[li] + Lp[(size_t)NBH * T_SEQ + li]);
  uint4 p0 = ((const uint4*)Op)[i];
  uint4 p1 = ((const uint4*)(Op + (size_t)M_ROWS * CDIM))[i];
  unsigned pw0[4] = {p0.x, p0.y, p0.z, p0.w};
  unsigned pw1[4] = {p1.x, p1.y, p1.z, p1.w};
  unsigned ow[4];
#pragma unroll
  for (int k = 0; k < 4; ++k) {
    float a0 = __builtin_bit_cast(float, pw0[k] << 16);
    float a1 = __builtin_bit_cast(float, pw0[k] & 0xFFFF0000u);
    float b0 = __builtin_bit_cast(float, pw1[k] << 16);
    float b1 = __builtin_bit_cast(float, pw1[k] & 0xFFFF0000u);
    unsigned short lo = f2bf((a0 + b0) * inv);
    unsigned short hiw = f2bf((a1 + b1) * inv);
    ow[k] = (unsigned)lo | ((unsigned)hiw << 16);
  }
  uint4 o; o.x = ow[0]; o.y = ow[1]; o.z = ow[2]; o.w = ow[3];
  ((uint4*)Ob)[i] = o;
}

// ---------------- kernel 5: proj GEMM  [8192][768] @ [768][768] + bias -> f32 ----------------
__global__ __launch_bounds__(256) void k_proj(const unsigned short* __restrict__ A,
                                              const unsigned short* __restrict__ Bt,
                                              const float* __restrict__ bias,
                                              float* __restrict__ out) {
  __shared__ short As[128 * 64];
  __shared__ short Bs[128 * 64];
  const int tid = threadIdx.x;
  const int wave = tid >> 6, lane = tid & 63;
  const int wr = wave >> 1, wc = wave & 1;
  // XCD-aware swizzle (m204, 384 = 8*48)
  const int lin = blockIdx.y * 6 + blockIdx.x;
  const int wg = (lin & 7) * 48 + (lin >> 3);
  const int m0 = (wg / 6) * 128, n0 = (wg % 6) * 128;

  f32x4 acc[4][4] = {};

#pragma unroll 1
  for (int k0 = 0; k0 < 768; k0 += 64) {
#pragma unroll
    for (int it = 0; it < 4; ++it) {
      int chunk = wave * 4 + it;
      int slot = chunk * 64 + lane;
      int row = slot >> 3, j = slot & 7;
      int kcol = k0 + ((j ^ (row & 7)) << 3);
      gld_lds16(A  + (size_t)(m0 + row) * 768 + kcol, &As[chunk * 512]);
      gld_lds16(Bt + (size_t)(n0 + row) * 768 + kcol, &Bs[chunk * 512]);
    }
    __syncthreads();
#pragma unroll
    for (int kk = 0; kk < 2; ++kk) {
      bf16x8 af[4], bfr[4];
      int cbl = kk * 4 + (lane >> 4);
#pragma unroll
      for (int mi = 0; mi < 4; ++mi) {
        int row = wr * 64 + mi * 16 + (lane & 15);
        af[mi] = *(const bf16x8*)&As[(row * 8 + (cbl ^ (row & 7))) * 8];
      }
#pragma unroll
      for (int ni = 0; ni < 4; ++ni) {
        int row = wc * 64 + ni * 16 + (lane & 15);
        bfr[ni] = *(const bf16x8*)&Bs[(row * 8 + (cbl ^ (row & 7))) * 8];
      }
#pragma unroll
      for (int mi = 0; mi < 4; ++mi)
#pragma unroll
        for (int ni = 0; ni < 4; ++ni)
          acc[mi][ni] = __builtin_amdgcn_mfma_f32_16x16x32_bf16(af[mi], bfr[ni], acc[mi][ni], 0, 0, 0);
    }
    __syncthreads();
  }

#pragma unroll
  for (int ni = 0; ni < 4; ++ni) {
    int col = n0 + wc * 64 + ni * 16 + (lane & 15);
    float bi = bias[col];
#pragma unroll
    for (int mi = 0; mi < 4; ++mi) {
      int mt = m0 + wr * 64 + mi * 16 + ((lane >> 4) << 2);
#pragma unroll
      for (int r = 0; r < 4; ++r)
        out[(size_t)(mt + r) * CDIM + col] = acc[mi][ni][r] + bi;
    }
  }
}

extern "C" void kernel_launch(void* const* d_in, const int* in_sizes, int n_in,
                              void* d_out, int out_size, void* d_ws, size_t ws_size,
                              hipStream_t stream) {
  const float* x  = (const float*)d_in[0];
  const float* Wa = (const float*)d_in[1];
  const float* ba = (const float*)d_in[2];
  const float* Wp = (const float*)d_in[3];
  const float* bp = (const float*)d_in[4];

  char* ws = (char*)d_ws;
  unsigned short* xb  = (unsigned short*)(ws + OFF_XB);
  unsigned short* WaT = (unsigned short*)(ws + OFF_WAT);
  unsigned short* WpT = (unsigned short*)(ws + OFF_WPT);
  unsigned short* Qb  = (unsigned short*)(ws + OFF_Q);
  unsigned short* Kb  = (unsigned short*)(ws + OFF_K);
  unsigned short* Vtb = (unsigned short*)(ws + OFF_VT);
  unsigned short* Ob  = (unsigned short*)(ws + OFF_O);
  unsigned short* Opb = (unsigned short*)(ws + OFF_P);
  float*          Lpb = (float*)(ws + OFF_L);

  k_conv<<<3072, 256, 0, stream>>>(x, xb);
  k_transpose<<<dim3(36, 12), 256, 0, stream>>>(Wa, WaT, CDIM, 3 * CDIM);
  k_transpose<<<dim3(12, 12), 256, 0, stream>>>(Wp, WpT, CDIM, CDIM);
  k_qkv<<<dim3(18, 64), 256, 0, stream>>>(xb, WaT, ba, Qb, Kb, Vtb);
  k_attn<<<dim3(16, 24, 2), 256, 0, stream>>>(Qb, Kb, Vtb, Opb, Lpb);
  k_combine<<<3072, 256, 0, stream>>>(Opb, Lpb, Ob);
  k_proj<<<dim3(6, 64), 256, 0, stream>>>(Ob, WpT, bp, (float*)d_out);
}

// Round 24
// 209.074 us; speedup vs baseline: 5.2418x; 5.2418x over previous
//
#include <hip/hip_runtime.h>
#include <cstdint>
#include <cstddef>

#define DEV static __device__ __forceinline__

typedef __attribute__((ext_vector_type(8))) short bf16x8;
typedef __attribute__((ext_vector_type(4))) float f32x4;
typedef __attribute__((ext_vector_type(16))) float f32x16;

#define T_SEQ 4096
#define CDIM  768
#define NH    12
#define HD    64
#define NBH   24            // B * NH
#define M_ROWS 8192         // B * T

// ---- workspace layout (bytes) ----
#define OFF_XB   0ull
#define OFF_WAT  (OFF_XB  + (size_t)M_ROWS * CDIM * 2)       // xb: [8192][768] bf16
#define OFF_WPT  (OFF_WAT + (size_t)(3*CDIM) * CDIM * 2)     // WaT: [2304][768] bf16
#define OFF_Q    (OFF_WPT + (size_t)CDIM * CDIM * 2)         // WpT: [768][768] bf16
#define OFF_K    (OFF_Q   + (size_t)NBH * T_SEQ * HD * 2)    // Q: [24][4096][64] bf16 (pre-scaled by log2e/8)
#define OFF_VT   (OFF_K   + (size_t)NBH * T_SEQ * HD * 2)    // K: [24][4096][64] bf16
#define OFF_O    (OFF_VT  + (size_t)NBH * HD * T_SEQ * 2)    // Vt: [24][64][4096] bf16 (key cols bit2<->bit3 permuted)
#define OFF_P    (OFF_O   + (size_t)M_ROWS * CDIM * 2)       // O (combined): [8192][768] bf16
#define OFF_L    (OFF_P   + 2ull * M_ROWS * CDIM * 2)        // Op partials: [2][8192][768] bf16
// Lp partials: [2][24][4096] f32

DEV unsigned short f2bf(float f) {            // RTNE f32 -> bf16
  unsigned u = __builtin_bit_cast(unsigned, f);
  u += 0x7FFFu + ((u >> 16) & 1u);
  return (unsigned short)(u >> 16);
}

DEV void gld_lds16(const void* g, void* l) {  // async global->LDS, 16B/lane, dest = wave-uniform base + lane*16
  __builtin_amdgcn_global_load_lds(
      (const __attribute__((address_space(1))) void*)g,
      (__attribute__((address_space(3))) void*)l, 16, 0, 0);
}

// Atomic 8x cvt_pk blob: all cvts contiguous (no MFMA can be scheduled between them)
// + s_nop 3 tail so every output has >=4 wait states before any consuming MFMA.
DEV void cvt8(const f32x16& s, unsigned* w) {
  asm("v_cvt_pk_bf16_f32 %0, %8, %9\n\t"
      "v_cvt_pk_bf16_f32 %1, %10, %11\n\t"
      "v_cvt_pk_bf16_f32 %2, %12, %13\n\t"
      "v_cvt_pk_bf16_f32 %3, %14, %15\n\t"
      "v_cvt_pk_bf16_f32 %4, %16, %17\n\t"
      "v_cvt_pk_bf16_f32 %5, %18, %19\n\t"
      "v_cvt_pk_bf16_f32 %6, %20, %21\n\t"
      "v_cvt_pk_bf16_f32 %7, %22, %23\n\t"
      "s_nop 3"
      : "=&v"(w[0]), "=&v"(w[1]), "=&v"(w[2]), "=&v"(w[3]),
        "=&v"(w[4]), "=&v"(w[5]), "=&v"(w[6]), "=&v"(w[7])
      : "v"(s[0]), "v"(s[1]), "v"(s[2]), "v"(s[3]),
        "v"(s[4]), "v"(s[5]), "v"(s[6]), "v"(s[7]),
        "v"(s[8]), "v"(s[9]), "v"(s[10]), "v"(s[11]),
        "v"(s[12]), "v"(s[13]), "v"(s[14]), "v"(s[15]));
}

// ---------------- kernel 1: cast x f32 -> bf16 ----------------
__global__ __launch_bounds__(256) void k_conv(const float* __restrict__ in,
                                              unsigned short* __restrict__ out) {
  int i = blockIdx.x * 256 + threadIdx.x;
  const float4* p = (const float4*)in;
  float4 a = p[i * 2], b = p[i * 2 + 1];
  uint4 o;
  o.x = (unsigned)f2bf(a.x) | ((unsigned)f2bf(a.y) << 16);
  o.y = (unsigned)f2bf(a.z) | ((unsigned)f2bf(a.w) << 16);
  o.z = (unsigned)f2bf(b.x) | ((unsigned)f2bf(b.y) << 16);
  o.w = (unsigned)f2bf(b.z) | ((unsigned)f2bf(b.w) << 16);
  ((uint4*)out)[i] = o;
}

// ---------------- kernel 2: transpose [R][C] f32 -> [C][R] bf16 ----------------
__global__ __launch_bounds__(256) void k_transpose(const float* __restrict__ in,
                                                   unsigned short* __restrict__ out,
                                                   int R, int C) {
  __shared__ float tile[64][65];
  int c0 = blockIdx.x * 64, r0 = blockIdx.y * 64;
  int tid = threadIdx.x;
  for (int i = tid; i < 4096; i += 256) {
    int r = i >> 6, c = i & 63;
    tile[r][c] = in[(size_t)(r0 + r) * C + c0 + c];
  }
  __syncthreads();
  for (int i = tid; i < 4096; i += 256) {
    int c = i >> 6, r = i & 63;
    out[(size_t)(c0 + c) * R + r0 + r] = f2bf(tile[r][c]);
  }
}

// ---------------- kernel 3: QKV GEMM  [8192][768] @ [768][2304] (+bias) ----------------
// Epilogue staged through LDS (reusing the 32 KB staging buffer) so all Q/K/Vt stores
// are coalesced b128 (r22: -11.5 us vs scalar scatter).
__global__ __launch_bounds__(256) void k_qkv(const unsigned short* __restrict__ A,
                                             const unsigned short* __restrict__ Bt,
                                             const float* __restrict__ bias,
                                             unsigned short* __restrict__ Qo,
                                             unsigned short* __restrict__ Ko,
                                             unsigned short* __restrict__ Vt) {
  __shared__ short LDSBUF[2][128 * 64];   // As | Bs; reused as 128x128 bf16 in the epilogue
  short* As = &LDSBUF[0][0];
  short* Bs = &LDSBUF[1][0];
  const int tid = threadIdx.x;
  const int wave = tid >> 6, lane = tid & 63;
  const int wr = wave >> 1, wc = wave & 1;
  // XCD-aware swizzle (m204, 1152 = 8*144)
  const int lin = blockIdx.y * 18 + blockIdx.x;
  const int wg = (lin & 7) * 144 + (lin >> 3);
  const int m0 = (wg / 18) * 128, n0 = (wg % 18) * 128;

  f32x4 acc[4][4] = {};

#pragma unroll 1
  for (int k0 = 0; k0 < 768; k0 += 64) {
#pragma unroll
    for (int it = 0; it < 4; ++it) {
      int chunk = wave * 4 + it;
      int slot = chunk * 64 + lane;
      int row = slot >> 3, j = slot & 7;
      int kcol = k0 + ((j ^ (row & 7)) << 3);
      gld_lds16(A  + (size_t)(m0 + row) * 768 + kcol, &As[chunk * 512]);
      gld_lds16(Bt + (size_t)(n0 + row) * 768 + kcol, &Bs[chunk * 512]);
    }
    __syncthreads();
#pragma unroll
    for (int kk = 0; kk < 2; ++kk) {
      bf16x8 af[4], bfr[4];
      int cbl = kk * 4 + (lane >> 4);
#pragma unroll
      for (int mi = 0; mi < 4; ++mi) {
        int row = wr * 64 + mi * 16 + (lane & 15);
        af[mi] = *(const bf16x8*)&As[(row * 8 + (cbl ^ (row & 7))) * 8];
      }
#pragma unroll
      for (int ni = 0; ni < 4; ++ni) {
        int row = wc * 64 + ni * 16 + (lane & 15);
        bfr[ni] = *(const bf16x8*)&Bs[(row * 8 + (cbl ^ (row & 7))) * 8];
      }
#pragma unroll
      for (int mi = 0; mi < 4; ++mi)
#pragma unroll
        for (int ni = 0; ni < 4; ++ni)
          acc[mi][ni] = __builtin_amdgcn_mfma_f32_16x16x32_bf16(af[mi], bfr[ni], acc[mi][ni], 0, 0, 0);
    }
    __syncthreads();
  }

  // ---- epilogue via LDS: coalesced stores ----
  __syncthreads();                       // done with As/Bs staging contents
  char* T = (char*)&LDSBUF[0][0];        // 128 rows x 256 B (bf16 x 128), XOR-swizzled chunks
  const int which = n0 / 768;
  const int hbase = (n0 - which * 768) >> 6;   // first of the 2 heads in this 128-col tile
  const int b = m0 >> 12, t0 = m0 & 4095;

  if (which < 2) {
    const float qs = (which == 0) ? 0.18033688011112042f : 1.0f;  // Q pre-scaled by log2e/8
#pragma unroll
    for (int ni = 0; ni < 4; ++ni) {
      int colL = wc * 64 + ni * 16 + (lane & 15);
      float bi = bias[n0 + colL];
#pragma unroll
      for (int mi = 0; mi < 4; ++mi) {
#pragma unroll
        for (int r = 0; r < 4; ++r) {
          int mL = wr * 64 + mi * 16 + ((lane >> 4) << 2) + r;
          *(unsigned short*)(T + mL * 256 + ((colL * 2) ^ ((mL & 7) << 4))) =
              f2bf((acc[mi][ni][r] + bi) * qs);
        }
      }
    }
    __syncthreads();
    unsigned short* OUT = (which == 0) ? Qo : Ko;
#pragma unroll
    for (int p = 0; p < 8; ++p) {
      int row = p * 16 + (tid >> 4);     // t_local
      int c = tid & 15;                  // 8-elem chunk of the 128 cols
      bf16x8 v = *(const bf16x8*)(T + row * 256 + (((c ^ (row & 7)) << 4)));
      int h = hbase + (c >> 3), d0 = (c & 7) * 8;
      size_t bh = (size_t)(b * NH + h);
      *(bf16x8*)&OUT[bh * (size_t)(T_SEQ * HD) + (size_t)(t0 + row) * HD + d0] = v;
    }
  } else {
    // Vt: stage TRANSPOSED with the bit2<->3 t-permute, store rows of 128 consecutive t
#pragma unroll
    for (int ni = 0; ni < 4; ++ni) {
      int colL = wc * 64 + ni * 16 + (lane & 15);
      float bi = bias[n0 + colL];
#pragma unroll
      for (int mi = 0; mi < 4; ++mi) {
#pragma unroll
        for (int r = 0; r < 4; ++r) {
          int mL = wr * 64 + mi * 16 + ((lane >> 4) << 2) + r;
          int mp = (mL & ~12) | ((mL & 4) << 1) | ((mL & 8) >> 1);   // t-permute (local bits)
          *(unsigned short*)(T + colL * 256 + ((mp * 2) ^ ((colL & 7) << 4))) =
              f2bf(acc[mi][ni][r] + bi);
        }
      }
    }
    __syncthreads();
#pragma unroll
    for (int p = 0; p < 8; ++p) {
      int row = p * 16 + (tid >> 4);     // colLocal = (head,d)
      int c = tid & 15;                  // 8-elem chunk of the 128 t
      bf16x8 v = *(const bf16x8*)(T + row * 256 + (((c ^ (row & 7)) << 4)));
      int h = hbase + (row >> 6), d = row & 63;
      size_t bh = (size_t)(b * NH + h);
      *(bf16x8*)&Vt[bh * (size_t)(T_SEQ * HD) + (size_t)d * T_SEQ + t0 + c * 8] = v;
    }
  }
}

// ---------------- kernel 4: flash attention (4 waves x 64 q/wave, K-SPLIT=2) ----------------
// grid (16 qtiles of 256 q, 24 bh, 2 ks), XCD-swizzled. Each wave owns 64 queries
// (2 Q-slices); K/V LDS reads are CSE'd across slices (r18: conflicts halved).
// __launch_bounds__(256,2) is REQUIRED: cap 170 (r20) and cap 128 (r23) both spill the
// accumulators to scratch (GB-scale FETCH/WRITE). Loose cap -> allocator lands at 116 VGPR.
__global__ __launch_bounds__(256, 2) void k_attn(const unsigned short* __restrict__ Q,
                                                 const unsigned short* __restrict__ K,
                                                 const unsigned short* __restrict__ Vt,
                                                 unsigned short* __restrict__ Op,
                                                 float* __restrict__ Lp) {
  __shared__ char ldsb[2][16384];   // [buf][ K tile 8 KiB | Vt tile 8 KiB ], XOR-swizzled
  const int tid = threadIdx.x, wave = tid >> 6, lane = tid & 63;
  const int hi = lane >> 5, l31 = lane & 31;
  // XCD-aware swizzle (m204, 384 = 8*48): XCD x owns bh [3x, 3x+3)
  const int lin = blockIdx.y * 16 + blockIdx.x;
  const int wg = (lin & 7) * 48 + (lin >> 3);
  const int qt = wg & 15, bh = wg >> 4, ks = blockIdx.z;
  const int b = bh / NH, h = bh % NH;
  const size_t base = (size_t)bh * T_SEQ * HD;
  const int q0 = qt * 256 + wave * 64;     // this wave's 64 queries: slices +0..31, +32..63

  // Q fragments (B-operand) per slice: col=q=l31, k(d) = 16t + 8*hi + j
  bf16x8 aq[2][4];
#pragma unroll
  for (int qf = 0; qf < 2; ++qf)
#pragma unroll
    for (int t = 0; t < 4; ++t)
      aq[qf][t] = *(const bf16x8*)&Q[base + (size_t)(q0 + qf * 32 + l31) * HD + t * 16 + hi * 8];

  // hoisted LDS byte offsets (lane-only)
  int koff[4];
#pragma unroll
  for (int t = 0; t < 4; ++t)
    koff[t] = l31 * 128 + ((((t << 1) | hi) ^ (l31 & 7)) << 4);
  int voff[2][2];
#pragma unroll
  for (int kb = 0; kb < 2; ++kb)
#pragma unroll
    for (int kss = 0; kss < 2; ++kss)
      voff[kb][kss] = ((((kb << 2) | (kss << 1) | hi) ^ (l31 & 7)) << 4) + l31 * 128;

  f32x16 oacc[2][2] = {};    // [qf][db]
  float lsum[2] = {0.f, 0.f};

  auto STAGE = [&](int bufi, int k0) {
#pragma unroll
    for (int it = 0; it < 2; ++it) {
      int chunk = wave * 2 + it;             // 4 waves x 2 = chunks 0..7
      int slot = chunk * 64 + lane;
      int row = slot >> 3, j = slot & 7;
      int ce = ((j ^ (row & 7)) << 3);       // pre-swizzled source column (elements)
      gld_lds16(K  + base + (size_t)(k0 + row) * HD + ce, ldsb[bufi] + chunk * 1024);
      gld_lds16(Vt + base + (size_t)row * T_SEQ + k0 + ce, ldsb[bufi] + 8192 + chunk * 1024);
    }
  };

  const int kt0 = ks * 32, ktEnd = kt0 + 32;
  STAGE(0, kt0 * 64);
  __syncthreads();

  int buf = 0;
#pragma unroll 1
  for (int kt = kt0; kt < ktEnd; ++kt) {
    if (kt + 1 < ktEnd) STAGE(buf ^ 1, (kt + 1) * 64);
    const char* Lq = ldsb[buf];
    const char* Vp = Lq + 8192;

#pragma unroll
    for (int qf = 0; qf < 2; ++qf) {
      // ---- QK0: S^T half 0 (keys kb=0)
      f32x16 s0 = {};
#pragma unroll
      for (int t = 0; t < 4; ++t) {
        bf16x8 kf = *(const bf16x8*)(Lq + koff[t]);
        s0 = __builtin_amdgcn_mfma_f32_32x32x16_bf16(kf, aq[qf][t], s0, 0, 0, 0);
      }
      // ---- exp2 + l-tree + cvt 0
#pragma unroll
      for (int r = 0; r < 16; ++r) s0[r] = __builtin_amdgcn_exp2f(s0[r]);
      {
        float a8[8];
#pragma unroll
        for (int i = 0; i < 8; ++i) a8[i] = s0[2 * i] + s0[2 * i + 1];
        float a4a = a8[0] + a8[1], a4b = a8[2] + a8[3], a4c = a8[4] + a8[5], a4d = a8[6] + a8[7];
        lsum[qf] += (a4a + a4b) + (a4c + a4d);
      }
      unsigned w0[8];
      cvt8(s0, w0);
      union { unsigned u[4]; bf16x8 v; } pf00, pf01;
      pf00.u[0] = w0[0]; pf00.u[1] = w0[1]; pf00.u[2] = w0[2]; pf00.u[3] = w0[3];
      pf01.u[0] = w0[4]; pf01.u[1] = w0[5]; pf01.u[2] = w0[6]; pf01.u[3] = w0[7];

      // ---- QK1: S^T half 1 (keys kb=1)
      f32x16 s1 = {};
#pragma unroll
      for (int t = 0; t < 4; ++t) {
        bf16x8 kf = *(const bf16x8*)(Lq + 4096 + koff[t]);
        s1 = __builtin_amdgcn_mfma_f32_32x32x16_bf16(kf, aq[qf][t], s1, 0, 0, 0);
      }

      // ---- PV0 (matrix pipe) — overlaps exp2/cvt 1 below
      {
        bf16x8 v0 = *(const bf16x8*)(Vp + voff[0][0]);
        bf16x8 v1 = *(const bf16x8*)(Vp + voff[0][1]);
        bf16x8 u0 = *(const bf16x8*)(Vp + 4096 + voff[0][0]);
        bf16x8 u1 = *(const bf16x8*)(Vp + 4096 + voff[0][1]);
        oacc[qf][0] = __builtin_amdgcn_mfma_f32_32x32x16_bf16(pf00.v, v0, oacc[qf][0], 0, 0, 0);
        oacc[qf][0] = __builtin_amdgcn_mfma_f32_32x32x16_bf16(pf01.v, v1, oacc[qf][0], 0, 0, 0);
        oacc[qf][1] = __builtin_amdgcn_mfma_f32_32x32x16_bf16(pf00.v, u0, oacc[qf][1], 0, 0, 0);
        oacc[qf][1] = __builtin_amdgcn_mfma_f32_32x32x16_bf16(pf01.v, u1, oacc[qf][1], 0, 0, 0);
      }

      // ---- exp2 + l-tree + cvt 1
#pragma unroll
      for (int r = 0; r < 16; ++r) s1[r] = __builtin_amdgcn_exp2f(s1[r]);
      {
        float a8[8];
#pragma unroll
        for (int i = 0; i < 8; ++i) a8[i] = s1[2 * i] + s1[2 * i + 1];
        float a4a = a8[0] + a8[1], a4b = a8[2] + a8[3], a4c = a8[4] + a8[5], a4d = a8[6] + a8[7];
        lsum[qf] += (a4a + a4b) + (a4c + a4d);
      }
      unsigned w1[8];
      cvt8(s1, w1);
      union { unsigned u[4]; bf16x8 v; } pf10, pf11;
      pf10.u[0] = w1[0]; pf10.u[1] = w1[1]; pf10.u[2] = w1[2]; pf10.u[3] = w1[3];
      pf11.u[0] = w1[4]; pf11.u[1] = w1[5]; pf11.u[2] = w1[6]; pf11.u[3] = w1[7];

      // ---- PV1
      {
        bf16x8 v0 = *(const bf16x8*)(Vp + voff[1][0]);
        bf16x8 v1 = *(const bf16x8*)(Vp + voff[1][1]);
        bf16x8 u0 = *(const bf16x8*)(Vp + 4096 + voff[1][0]);
        bf16x8 u1 = *(const bf16x8*)(Vp + 4096 + voff[1][1]);
        oacc[qf][0] = __builtin_amdgcn_mfma_f32_32x32x16_bf16(pf10.v, v0, oacc[qf][0], 0, 0, 0);
        oacc[qf][0] = __builtin_amdgcn_mfma_f32_32x32x16_bf16(pf11.v, v1, oacc[qf][0], 0, 0, 0);
        oacc[qf][1] = __builtin_amdgcn_mfma_f32_32x32x16_bf16(pf10.v, u0, oacc[qf][1], 0, 0, 0);
        oacc[qf][1] = __builtin_amdgcn_mfma_f32_32x32x16_bf16(pf11.v, u1, oacc[qf][1], 0, 0, 0);
      }
    }

    __syncthreads();
    buf ^= 1;
  }

  // epilogue: UNNORMALIZED partials. Op[ks][b*T+t][h*64+d] bf16; Lp[ks][bh][t] f32.
  // Combine hi-halves first, then lane l31 (hi==0) writes the full l for its query.
  unsigned short* OpS = Op + (size_t)ks * M_ROWS * CDIM;
  float* LpS = Lp + (size_t)ks * NBH * T_SEQ;
#pragma unroll
  for (int qf = 0; qf < 2; ++qf) {
    float l = lsum[qf];
    l += __shfl_xor(l, 32, 64);
    if (hi == 0) LpS[(size_t)bh * T_SEQ + (q0 + qf * 32 + l31)] = l;
#pragma unroll
    for (int r = 0; r < 16; ++r) {
      int t = q0 + qf * 32 + ((r & 3) + 8 * (r >> 2)) + 4 * hi;
      size_t rowb = (size_t)(b * T_SEQ + t) * CDIM + h * 64;
      OpS[rowb + l31]      = f2bf(oacc[qf][0][r]);
      OpS[rowb + 32 + l31] = f2bf(oacc[qf][1][r]);
    }
  }
}

// ---------------- kernel 4b: combine K-split partials  O = (O0+O1)/(l0+l1) ----------------
__global__ __launch_bounds__(256) void k_combine(const unsigned short* __restrict__ Op,
                                                 const float* __restrict__ Lp,
                                                 unsigned short* __restrict__ Ob) {
  int i = blockIdx.x * 256 + threadIdx.x;      // one 8-elem chunk; 8192*768/8/256 = 3072 blocks
  size_t e = (size_t)i * 8;
  int c = (int)(e % CDIM);
  int bt = (int)(e / CDIM);
  int t = bt & 4095, b = bt >> 12;
  int h = c >> 6;
  size_t li = (size_t)(b * NH + h) * T_SEQ + t;
  float inv = 1.0f / (Lp[li] + Lp[(size_t)NBH * T_SEQ + li]);
  uint4 p0 = ((const uint4*)Op)[i];
  uint4 p1 = ((const uint4*)(Op + (size_t)M_ROWS * CDIM))[i];
  unsigned pw0[4] = {p0.x, p0.y, p0.z, p0.w};
  unsigned pw1[4] = {p1.x, p1.y, p1.z, p1.w};
  unsigned ow[4];
#pragma unroll
  for (int k = 0; k < 4; ++k) {
    float a0 = __builtin_bit_cast(float, pw0[k] << 16);
    float a1 = __builtin_bit_cast(float, pw0[k] & 0xFFFF0000u);
    float b0 = __builtin_bit_cast(float, pw1[k] << 16);
    float b1 = __builtin_bit_cast(float, pw1[k] & 0xFFFF0000u);
    unsigned short lo = f2bf((a0 + b0) * inv);
    unsigned short hiw = f2bf((a1 + b1) * inv);
    ow[k] = (unsigned)lo | ((unsigned)hiw << 16);
  }
  uint4 o; o.x = ow[0]; o.y = ow[1]; o.z = ow[2]; o.w = ow[3];
  ((uint4*)Ob)[i] = o;
}

// ---------------- kernel 5: proj GEMM  [8192][768] @ [768][768] + bias -> f32 ----------------
__global__ __launch_bounds__(256) void k_proj(const unsigned short* __restrict__ A,
                                              const unsigned short* __restrict__ Bt,
                                              const float* __restrict__ bias,
                                              float* __restrict__ out) {
  __shared__ short As[128 * 64];
  __shared__ short Bs[128 * 64];
  const int tid = threadIdx.x;
  const int wave = tid >> 6, lane = tid & 63;
  const int wr = wave >> 1, wc = wave & 1;
  // XCD-aware swizzle (m204, 384 = 8*48)
  const int lin = blockIdx.y * 6 + blockIdx.x;
  const int wg = (lin & 7) * 48 + (lin >> 3);
  const int m0 = (wg / 6) * 128, n0 = (wg % 6) * 128;

  f32x4 acc[4][4] = {};

#pragma unroll 1
  for (int k0 = 0; k0 < 768; k0 += 64) {
#pragma unroll
    for (int it = 0; it < 4; ++it) {
      int chunk = wave * 4 + it;
      int slot = chunk * 64 + lane;
      int row = slot >> 3, j = slot & 7;
      int kcol = k0 + ((j ^ (row & 7)) << 3);
      gld_lds16(A  + (size_t)(m0 + row) * 768 + kcol, &As[chunk * 512]);
      gld_lds16(Bt + (size_t)(n0 + row) * 768 + kcol, &Bs[chunk * 512]);
    }
    __syncthreads();
#pragma unroll
    for (int kk = 0; kk < 2; ++kk) {
      bf16x8 af[4], bfr[4];
      int cbl = kk * 4 + (lane >> 4);
#pragma unroll
      for (int mi = 0; mi < 4; ++mi) {
        int row = wr * 64 + mi * 16 + (lane & 15);
        af[mi] = *(const bf16x8*)&As[(row * 8 + (cbl ^ (row & 7))) * 8];
      }
#pragma unroll
      for (int ni = 0; ni < 4; ++ni) {
        int row = wc * 64 + ni * 16 + (lane & 15);
        bfr[ni] = *(const bf16x8*)&Bs[(row * 8 + (cbl ^ (row & 7))) * 8];
      }
#pragma unroll
      for (int mi = 0; mi < 4; ++mi)
#pragma unroll
        for (int ni = 0; ni < 4; ++ni)
          acc[mi][ni] = __builtin_amdgcn_mfma_f32_16x16x32_bf16(af[mi], bfr[ni], acc[mi][ni], 0, 0, 0);
    }
    __syncthreads();
  }

#pragma unroll
  for (int ni = 0; ni < 4; ++ni) {
    int col = n0 + wc * 64 + ni * 16 + (lane & 15);
    float bi = bias[col];
#pragma unroll
    for (int mi = 0; mi < 4; ++mi) {
      int mt = m0 + wr * 64 + mi * 16 + ((lane >> 4) << 2);
#pragma unroll
      for (int r = 0; r < 4; ++r)
        out[(size_t)(mt + r) * CDIM + col] = acc[mi][ni][r] + bi;
    }
  }
}

extern "C" void kernel_launch(void* const* d_in, const int* in_sizes, int n_in,
                              void* d_out, int out_size, void* d_ws, size_t ws_size,
                              hipStream_t stream) {
  const float* x  = (const float*)d_in[0];
  const float* Wa = (const float*)d_in[1];
  const float* ba = (const float*)d_in[2];
  const float* Wp = (const float*)d_in[3];
  const float* bp = (const float*)d_in[4];

  char* ws = (char*)d_ws;
  unsigned short* xb  = (unsigned short*)(ws + OFF_XB);
  unsigned short* WaT = (unsigned short*)(ws + OFF_WAT);
  unsigned short* WpT = (unsigned short*)(ws + OFF_WPT);
  unsigned short* Qb  = (unsigned short*)(ws + OFF_Q);
  unsigned short* Kb  = (unsigned short*)(ws + OFF_K);
  unsigned short* Vtb = (unsigned short*)(ws + OFF_VT);
  unsigned short* Ob  = (unsigned short*)(ws + OFF_O);
  unsigned short* Opb = (unsigned short*)(ws + OFF_P);
  float*          Lpb = (float*)(ws + OFF_L);

  k_conv<<<3072, 256, 0, stream>>>(x, xb);
  k_transpose<<<dim3(36, 12), 256, 0, stream>>>(Wa, WaT, CDIM, 3 * CDIM);
  k_transpose<<<dim3(12, 12), 256, 0, stream>>>(Wp, WpT, CDIM, CDIM);
  k_qkv<<<dim3(18, 64), 256, 0, stream>>>(xb, WaT, ba, Qb, Kb, Vtb);
  k_attn<<<dim3(16, 24, 2), 256, 0, stream>>>(Qb, Kb, Vtb, Opb, Lpb);
  k_combine<<<3072, 256, 0, stream>>>(Opb, Lpb, Ob);
  k_proj<<<dim3(6, 64), 256, 0, stream>>>(Ob, WpT, bp, (float*)d_out);
}

// Round 25
// 206.709 us; speedup vs baseline: 5.3018x; 1.0114x over previous
//
#include <hip/hip_runtime.h>
#include <cstdint>
#include <cstddef>

#define DEV static __device__ __forceinline__

typedef __attribute__((ext_vector_type(8))) short bf16x8;
typedef __attribute__((ext_vector_type(4))) float f32x4;
typedef __attribute__((ext_vector_type(16))) float f32x16;

#define T_SEQ 4096
#define CDIM  768
#define NH    12
#define HD    64
#define NBH   24            // B * NH
#define M_ROWS 8192         // B * T

// ---- workspace layout (bytes) ----
#define OFF_XB   0ull
#define OFF_WAT  (OFF_XB  + (size_t)M_ROWS * CDIM * 2)       // xb: [8192][768] bf16
#define OFF_WPT  (OFF_WAT + (size_t)(3*CDIM) * CDIM * 2)     // WaT: [2304][768] bf16
#define OFF_Q    (OFF_WPT + (size_t)CDIM * CDIM * 2)         // WpT: [768][768] bf16
#define OFF_K    (OFF_Q   + (size_t)NBH * T_SEQ * HD * 2)    // Q: [24][4096][64] bf16 (pre-scaled by log2e/8)
#define OFF_VT   (OFF_K   + (size_t)NBH * T_SEQ * HD * 2)    // K: [24][4096][64] bf16
#define OFF_O    (OFF_VT  + (size_t)NBH * HD * T_SEQ * 2)    // Vt: [24][64][4096] bf16 (key cols bit2<->bit3 permuted)
#define OFF_P    (OFF_O   + (size_t)M_ROWS * CDIM * 2)       // O (combined): [8192][768] bf16
#define OFF_L    (OFF_P   + 2ull * M_ROWS * CDIM * 2)        // Op partials: [2][8192][768] bf16
// Lp partials: [2][24][4096] f32

DEV unsigned short f2bf(float f) {            // RTNE f32 -> bf16
  unsigned u = __builtin_bit_cast(unsigned, f);
  u += 0x7FFFu + ((u >> 16) & 1u);
  return (unsigned short)(u >> 16);
}

DEV void gld_lds16(const void* g, void* l) {  // async global->LDS, 16B/lane, dest = wave-uniform base + lane*16
  __builtin_amdgcn_global_load_lds(
      (const __attribute__((address_space(1))) void*)g,
      (__attribute__((address_space(3))) void*)l, 16, 0, 0);
}

// Atomic 8x cvt_pk blob: all cvts contiguous (no MFMA can be scheduled between them)
// + s_nop 3 tail so every output has >=4 wait states before any consuming MFMA.
DEV void cvt8(const f32x16& s, unsigned* w) {
  asm("v_cvt_pk_bf16_f32 %0, %8, %9\n\t"
      "v_cvt_pk_bf16_f32 %1, %10, %11\n\t"
      "v_cvt_pk_bf16_f32 %2, %12, %13\n\t"
      "v_cvt_pk_bf16_f32 %3, %14, %15\n\t"
      "v_cvt_pk_bf16_f32 %4, %16, %17\n\t"
      "v_cvt_pk_bf16_f32 %5, %18, %19\n\t"
      "v_cvt_pk_bf16_f32 %6, %20, %21\n\t"
      "v_cvt_pk_bf16_f32 %7, %22, %23\n\t"
      "s_nop 3"
      : "=&v"(w[0]), "=&v"(w[1]), "=&v"(w[2]), "=&v"(w[3]),
        "=&v"(w[4]), "=&v"(w[5]), "=&v"(w[6]), "=&v"(w[7])
      : "v"(s[0]), "v"(s[1]), "v"(s[2]), "v"(s[3]),
        "v"(s[4]), "v"(s[5]), "v"(s[6]), "v"(s[7]),
        "v"(s[8]), "v"(s[9]), "v"(s[10]), "v"(s[11]),
        "v"(s[12]), "v"(s[13]), "v"(s[14]), "v"(s[15]));
}

// ---------------- kernel 1: cast x f32 -> bf16 ----------------
__global__ __launch_bounds__(256) void k_conv(const float* __restrict__ in,
                                              unsigned short* __restrict__ out) {
  int i = blockIdx.x * 256 + threadIdx.x;
  const float4* p = (const float4*)in;
  float4 a = p[i * 2], b = p[i * 2 + 1];
  uint4 o;
  o.x = (unsigned)f2bf(a.x) | ((unsigned)f2bf(a.y) << 16);
  o.y = (unsigned)f2bf(a.z) | ((unsigned)f2bf(a.w) << 16);
  o.z = (unsigned)f2bf(b.x) | ((unsigned)f2bf(b.y) << 16);
  o.w = (unsigned)f2bf(b.z) | ((unsigned)f2bf(b.w) << 16);
  ((uint4*)out)[i] = o;
}

// ---------------- kernel 2: transpose [R][C] f32 -> [C][R] bf16 ----------------
__global__ __launch_bounds__(256) void k_transpose(const float* __restrict__ in,
                                                   unsigned short* __restrict__ out,
                                                   int R, int C) {
  __shared__ float tile[64][65];
  int c0 = blockIdx.x * 64, r0 = blockIdx.y * 64;
  int tid = threadIdx.x;
  for (int i = tid; i < 4096; i += 256) {
    int r = i >> 6, c = i & 63;
    tile[r][c] = in[(size_t)(r0 + r) * C + c0 + c];
  }
  __syncthreads();
  for (int i = tid; i < 4096; i += 256) {
    int c = i >> 6, r = i & 63;
    out[(size_t)(c0 + c) * R + r0 + r] = f2bf(tile[r][c]);
  }
}

// ---------------- kernel 3: QKV GEMM  [8192][768] @ [768][2304] (+bias) ----------------
// Epilogue staged through LDS (reusing the 32 KB staging buffer) so all Q/K/Vt stores
// are coalesced b128 (r22: -11.5 us vs scalar scatter).
__global__ __launch_bounds__(256) void k_qkv(const unsigned short* __restrict__ A,
                                             const unsigned short* __restrict__ Bt,
                                             const float* __restrict__ bias,
                                             unsigned short* __restrict__ Qo,
                                             unsigned short* __restrict__ Ko,
                                             unsigned short* __restrict__ Vt) {
  __shared__ short LDSBUF[2][128 * 64];   // As | Bs; reused as 128x128 bf16 in the epilogue
  short* As = &LDSBUF[0][0];
  short* Bs = &LDSBUF[1][0];
  const int tid = threadIdx.x;
  const int wave = tid >> 6, lane = tid & 63;
  const int wr = wave >> 1, wc = wave & 1;
  // XCD-aware swizzle (m204, 1152 = 8*144)
  const int lin = blockIdx.y * 18 + blockIdx.x;
  const int wg = (lin & 7) * 144 + (lin >> 3);
  const int m0 = (wg / 18) * 128, n0 = (wg % 18) * 128;

  f32x4 acc[4][4] = {};

#pragma unroll 1
  for (int k0 = 0; k0 < 768; k0 += 64) {
#pragma unroll
    for (int it = 0; it < 4; ++it) {
      int chunk = wave * 4 + it;
      int slot = chunk * 64 + lane;
      int row = slot >> 3, j = slot & 7;
      int kcol = k0 + ((j ^ (row & 7)) << 3);
      gld_lds16(A  + (size_t)(m0 + row) * 768 + kcol, &As[chunk * 512]);
      gld_lds16(Bt + (size_t)(n0 + row) * 768 + kcol, &Bs[chunk * 512]);
    }
    __syncthreads();
#pragma unroll
    for (int kk = 0; kk < 2; ++kk) {
      bf16x8 af[4], bfr[4];
      int cbl = kk * 4 + (lane >> 4);
#pragma unroll
      for (int mi = 0; mi < 4; ++mi) {
        int row = wr * 64 + mi * 16 + (lane & 15);
        af[mi] = *(const bf16x8*)&As[(row * 8 + (cbl ^ (row & 7))) * 8];
      }
#pragma unroll
      for (int ni = 0; ni < 4; ++ni) {
        int row = wc * 64 + ni * 16 + (lane & 15);
        bfr[ni] = *(const bf16x8*)&Bs[(row * 8 + (cbl ^ (row & 7))) * 8];
      }
#pragma unroll
      for (int mi = 0; mi < 4; ++mi)
#pragma unroll
        for (int ni = 0; ni < 4; ++ni)
          acc[mi][ni] = __builtin_amdgcn_mfma_f32_16x16x32_bf16(af[mi], bfr[ni], acc[mi][ni], 0, 0, 0);
    }
    __syncthreads();
  }

  // ---- epilogue via LDS: coalesced stores ----
  __syncthreads();                       // done with As/Bs staging contents
  char* T = (char*)&LDSBUF[0][0];        // 128 rows x 256 B (bf16 x 128), XOR-swizzled chunks
  const int which = n0 / 768;
  const int hbase = (n0 - which * 768) >> 6;   // first of the 2 heads in this 128-col tile
  const int b = m0 >> 12, t0 = m0 & 4095;

  if (which < 2) {
    const float qs = (which == 0) ? 0.18033688011112042f : 1.0f;  // Q pre-scaled by log2e/8
#pragma unroll
    for (int ni = 0; ni < 4; ++ni) {
      int colL = wc * 64 + ni * 16 + (lane & 15);
      float bi = bias[n0 + colL];
#pragma unroll
      for (int mi = 0; mi < 4; ++mi) {
#pragma unroll
        for (int r = 0; r < 4; ++r) {
          int mL = wr * 64 + mi * 16 + ((lane >> 4) << 2) + r;
          *(unsigned short*)(T + mL * 256 + ((colL * 2) ^ ((mL & 7) << 4))) =
              f2bf((acc[mi][ni][r] + bi) * qs);
        }
      }
    }
    __syncthreads();
    unsigned short* OUT = (which == 0) ? Qo : Ko;
#pragma unroll
    for (int p = 0; p < 8; ++p) {
      int row = p * 16 + (tid >> 4);     // t_local
      int c = tid & 15;                  // 8-elem chunk of the 128 cols
      bf16x8 v = *(const bf16x8*)(T + row * 256 + (((c ^ (row & 7)) << 4)));
      int h = hbase + (c >> 3), d0 = (c & 7) * 8;
      size_t bh = (size_t)(b * NH + h);
      *(bf16x8*)&OUT[bh * (size_t)(T_SEQ * HD) + (size_t)(t0 + row) * HD + d0] = v;
    }
  } else {
    // Vt: stage TRANSPOSED with the bit2<->3 t-permute, store rows of 128 consecutive t
#pragma unroll
    for (int ni = 0; ni < 4; ++ni) {
      int colL = wc * 64 + ni * 16 + (lane & 15);
      float bi = bias[n0 + colL];
#pragma unroll
      for (int mi = 0; mi < 4; ++mi) {
#pragma unroll
        for (int r = 0; r < 4; ++r) {
          int mL = wr * 64 + mi * 16 + ((lane >> 4) << 2) + r;
          int mp = (mL & ~12) | ((mL & 4) << 1) | ((mL & 8) >> 1);   // t-permute (local bits)
          *(unsigned short*)(T + colL * 256 + ((mp * 2) ^ ((colL & 7) << 4))) =
              f2bf(acc[mi][ni][r] + bi);
        }
      }
    }
    __syncthreads();
#pragma unroll
    for (int p = 0; p < 8; ++p) {
      int row = p * 16 + (tid >> 4);     // colLocal = (head,d)
      int c = tid & 15;                  // 8-elem chunk of the 128 t
      bf16x8 v = *(const bf16x8*)(T + row * 256 + (((c ^ (row & 7)) << 4)));
      int h = hbase + (row >> 6), d = row & 63;
      size_t bh = (size_t)(b * NH + h);
      *(bf16x8*)&Vt[bh * (size_t)(T_SEQ * HD) + (size_t)d * T_SEQ + t0 + c * 8] = v;
    }
  }
}

// ---------------- kernel 4: flash attention (4 waves x 64 q/wave, K-SPLIT=2) ----------------
// grid (16 qtiles of 256 q, 24 bh, 2 ks), XCD-swizzled. Each wave owns 64 queries
// (2 Q-slices); K/V LDS reads are CSE'd across slices (r18: conflicts halved).
// __launch_bounds__(256,2) is REQUIRED: cap 170 (r20) and cap 128 (r23) both spill the
// accumulators to scratch (GB-scale FETCH/WRITE). Loose cap -> allocator lands at 116 VGPR.
__global__ __launch_bounds__(256, 2) void k_attn(const unsigned short* __restrict__ Q,
                                                 const unsigned short* __restrict__ K,
                                                 const unsigned short* __restrict__ Vt,
                                                 unsigned short* __restrict__ Op,
                                                 float* __restrict__ Lp) {
  __shared__ char ldsb[2][16384];   // [buf][ K tile 8 KiB | Vt tile 8 KiB ], XOR-swizzled
  const int tid = threadIdx.x, wave = tid >> 6, lane = tid & 63;
  const int hi = lane >> 5, l31 = lane & 31;
  // XCD-aware swizzle (m204, 384 = 8*48): XCD x owns bh [3x, 3x+3)
  const int lin = blockIdx.y * 16 + blockIdx.x;
  const int wg = (lin & 7) * 48 + (lin >> 3);
  const int qt = wg & 15, bh = wg >> 4, ks = blockIdx.z;
  const int b = bh / NH, h = bh % NH;
  const size_t base = (size_t)bh * T_SEQ * HD;
  const int q0 = qt * 256 + wave * 64;     // this wave's 64 queries: slices +0..31, +32..63

  // Q fragments (B-operand) per slice: col=q=l31, k(d) = 16t + 8*hi + j
  bf16x8 aq[2][4];
#pragma unroll
  for (int qf = 0; qf < 2; ++qf)
#pragma unroll
    for (int t = 0; t < 4; ++t)
      aq[qf][t] = *(const bf16x8*)&Q[base + (size_t)(q0 + qf * 32 + l31) * HD + t * 16 + hi * 8];

  // hoisted LDS byte offsets (lane-only)
  int koff[4];
#pragma unroll
  for (int t = 0; t < 4; ++t)
    koff[t] = l31 * 128 + ((((t << 1) | hi) ^ (l31 & 7)) << 4);
  int voff[2][2];
#pragma unroll
  for (int kb = 0; kb < 2; ++kb)
#pragma unroll
    for (int kss = 0; kss < 2; ++kss)
      voff[kb][kss] = ((((kb << 2) | (kss << 1) | hi) ^ (l31 & 7)) << 4) + l31 * 128;

  f32x16 oacc[2][2] = {};    // [qf][db]
  float lsum[2] = {0.f, 0.f};

  auto STAGE = [&](int bufi, int k0) {
#pragma unroll
    for (int it = 0; it < 2; ++it) {
      int chunk = wave * 2 + it;             // 4 waves x 2 = chunks 0..7
      int slot = chunk * 64 + lane;
      int row = slot >> 3, j = slot & 7;
      int ce = ((j ^ (row & 7)) << 3);       // pre-swizzled source column (elements)
      gld_lds16(K  + base + (size_t)(k0 + row) * HD + ce, ldsb[bufi] + chunk * 1024);
      gld_lds16(Vt + base + (size_t)row * T_SEQ + k0 + ce, ldsb[bufi] + 8192 + chunk * 1024);
    }
  };

  const int kt0 = ks * 32, ktEnd = kt0 + 32;
  STAGE(0, kt0 * 64);
  __syncthreads();

  int buf = 0;
#pragma unroll 1
  for (int kt = kt0; kt < ktEnd; ++kt) {
    if (kt + 1 < ktEnd) STAGE(buf ^ 1, (kt + 1) * 64);
    const char* Lq = ldsb[buf];
    const char* Vp = Lq + 8192;

#pragma unroll
    for (int qf = 0; qf < 2; ++qf) {
      // ---- QK0: S^T half 0 (keys kb=0)
      f32x16 s0 = {};
#pragma unroll
      for (int t = 0; t < 4; ++t) {
        bf16x8 kf = *(const bf16x8*)(Lq + koff[t]);
        s0 = __builtin_amdgcn_mfma_f32_32x32x16_bf16(kf, aq[qf][t], s0, 0, 0, 0);
      }
      // ---- exp2 + l-tree + cvt 0
#pragma unroll
      for (int r = 0; r < 16; ++r) s0[r] = __builtin_amdgcn_exp2f(s0[r]);
      {
        float a8[8];
#pragma unroll
        for (int i = 0; i < 8; ++i) a8[i] = s0[2 * i] + s0[2 * i + 1];
        float a4a = a8[0] + a8[1], a4b = a8[2] + a8[3], a4c = a8[4] + a8[5], a4d = a8[6] + a8[7];
        lsum[qf] += (a4a + a4b) + (a4c + a4d);
      }
      unsigned w0[8];
      cvt8(s0, w0);
      union { unsigned u[4]; bf16x8 v; } pf00, pf01;
      pf00.u[0] = w0[0]; pf00.u[1] = w0[1]; pf00.u[2] = w0[2]; pf00.u[3] = w0[3];
      pf01.u[0] = w0[4]; pf01.u[1] = w0[5]; pf01.u[2] = w0[6]; pf01.u[3] = w0[7];

      // ---- QK1: S^T half 1 (keys kb=1)
      f32x16 s1 = {};
#pragma unroll
      for (int t = 0; t < 4; ++t) {
        bf16x8 kf = *(const bf16x8*)(Lq + 4096 + koff[t]);
        s1 = __builtin_amdgcn_mfma_f32_32x32x16_bf16(kf, aq[qf][t], s1, 0, 0, 0);
      }

      // ---- PV0 (matrix pipe) — overlaps exp2/cvt 1 below
      {
        bf16x8 v0 = *(const bf16x8*)(Vp + voff[0][0]);
        bf16x8 v1 = *(const bf16x8*)(Vp + voff[0][1]);
        bf16x8 u0 = *(const bf16x8*)(Vp + 4096 + voff[0][0]);
        bf16x8 u1 = *(const bf16x8*)(Vp + 4096 + voff[0][1]);
        oacc[qf][0] = __builtin_amdgcn_mfma_f32_32x32x16_bf16(pf00.v, v0, oacc[qf][0], 0, 0, 0);
        oacc[qf][0] = __builtin_amdgcn_mfma_f32_32x32x16_bf16(pf01.v, v1, oacc[qf][0], 0, 0, 0);
        oacc[qf][1] = __builtin_amdgcn_mfma_f32_32x32x16_bf16(pf00.v, u0, oacc[qf][1], 0, 0, 0);
        oacc[qf][1] = __builtin_amdgcn_mfma_f32_32x32x16_bf16(pf01.v, u1, oacc[qf][1], 0, 0, 0);
      }

      // ---- exp2 + l-tree + cvt 1
#pragma unroll
      for (int r = 0; r < 16; ++r) s1[r] = __builtin_amdgcn_exp2f(s1[r]);
      {
        float a8[8];
#pragma unroll
        for (int i = 0; i < 8; ++i) a8[i] = s1[2 * i] + s1[2 * i + 1];
        float a4a = a8[0] + a8[1], a4b = a8[2] + a8[3], a4c = a8[4] + a8[5], a4d = a8[6] + a8[7];
        lsum[qf] += (a4a + a4b) + (a4c + a4d);
      }
      unsigned w1[8];
      cvt8(s1, w1);
      union { unsigned u[4]; bf16x8 v; } pf10, pf11;
      pf10.u[0] = w1[0]; pf10.u[1] = w1[1]; pf10.u[2] = w1[2]; pf10.u[3] = w1[3];
      pf11.u[0] = w1[4]; pf11.u[1] = w1[5]; pf11.u[2] = w1[6]; pf11.u[3] = w1[7];

      // ---- PV1
      {
        bf16x8 v0 = *(const bf16x8*)(Vp + voff[1][0]);
        bf16x8 v1 = *(const bf16x8*)(Vp + voff[1][1]);
        bf16x8 u0 = *(const bf16x8*)(Vp + 4096 + voff[1][0]);
        bf16x8 u1 = *(const bf16x8*)(Vp + 4096 + voff[1][1]);
        oacc[qf][0] = __builtin_amdgcn_mfma_f32_32x32x16_bf16(pf10.v, v0, oacc[qf][0], 0, 0, 0);
        oacc[qf][0] = __builtin_amdgcn_mfma_f32_32x32x16_bf16(pf11.v, v1, oacc[qf][0], 0, 0, 0);
        oacc[qf][1] = __builtin_amdgcn_mfma_f32_32x32x16_bf16(pf10.v, u0, oacc[qf][1], 0, 0, 0);
        oacc[qf][1] = __builtin_amdgcn_mfma_f32_32x32x16_bf16(pf11.v, u1, oacc[qf][1], 0, 0, 0);
      }
    }

    __syncthreads();
    buf ^= 1;
  }

  // epilogue: UNNORMALIZED partials. Op[ks][b*T+t][h*64+d] bf16; Lp[ks][bh][t] f32.
  // Combine hi-halves first, then lane l31 (hi==0) writes the full l for its query.
  unsigned short* OpS = Op + (size_t)ks * M_ROWS * CDIM;
  float* LpS = Lp + (size_t)ks * NBH * T_SEQ;
#pragma unroll
  for (int qf = 0; qf < 2; ++qf) {
    float l = lsum[qf];
    l += __shfl_xor(l, 32, 64);
    if (hi == 0) LpS[(size_t)bh * T_SEQ + (q0 + qf * 32 + l31)] = l;
#pragma unroll
    for (int r = 0; r < 16; ++r) {
      int t = q0 + qf * 32 + ((r & 3) + 8 * (r >> 2)) + 4 * hi;
      size_t rowb = (size_t)(b * T_SEQ + t) * CDIM + h * 64;
      OpS[rowb + l31]      = f2bf(oacc[qf][0][r]);
      OpS[rowb + 32 + l31] = f2bf(oacc[qf][1][r]);
    }
  }
}

// ---------------- kernel 4b: combine K-split partials  O = (O0+O1)/(l0+l1) ----------------
__global__ __launch_bounds__(256) void k_combine(const unsigned short* __restrict__ Op,
                                                 const float* __restrict__ Lp,
                                                 unsigned short* __restrict__ Ob) {
  int i = blockIdx.x * 256 + threadIdx.x;      // one 8-elem chunk; 8192*768/8/256 = 3072 blocks
  size_t e = (size_t)i * 8;
  int c = (int)(e % CDIM);
  int bt = (int)(e / CDIM);
  int t = bt & 4095, b = bt >> 12;
  int h = c >> 6;
  size_t li = (size_t)(b * NH + h) * T_SEQ + t;
  float inv = 1.0f / (Lp[li] + Lp[(size_t)NBH * T_SEQ + li]);
  uint4 p0 = ((const uint4*)Op)[i];
  uint4 p1 = ((const uint4*)(Op + (size_t)M_ROWS * CDIM))[i];
  unsigned pw0[4] = {p0.x, p0.y, p0.z, p0.w};
  unsigned pw1[4] = {p1.x, p1.y, p1.z, p1.w};
  unsigned ow[4];
#pragma unroll
  for (int k = 0; k < 4; ++k) {
    float a0 = __builtin_bit_cast(float, pw0[k] << 16);
    float a1 = __builtin_bit_cast(float, pw0[k] & 0xFFFF0000u);
    float b0 = __builtin_bit_cast(float, pw1[k] << 16);
    float b1 = __builtin_bit_cast(float, pw1[k] & 0xFFFF0000u);
    unsigned short lo = f2bf((a0 + b0) * inv);
    unsigned short hiw = f2bf((a1 + b1) * inv);
    ow[k] = (unsigned)lo | ((unsigned)hiw << 16);
  }
  uint4 o; o.x = ow[0]; o.y = ow[1]; o.z = ow[2]; o.w = ow[3];
  ((uint4*)Ob)[i] = o;
}

// ---------------- kernel 5: proj GEMM  [8192][768] @ [768][768] + bias -> f32 ----------------
// BM=128 x BN=64 tiles -> grid 12x64 = 768 blocks = exactly 3 blocks/CU (the old 6x64 =
// 384 blocks left half the CUs idle during a second full tile pass). 768 = 8*96 XCD-swizzle.
__global__ __launch_bounds__(256) void k_proj(const unsigned short* __restrict__ A,
                                              const unsigned short* __restrict__ Bt,
                                              const float* __restrict__ bias,
                                              float* __restrict__ out) {
  __shared__ short As[128 * 64];
  __shared__ short Bs[64 * 64];
  const int tid = threadIdx.x;
  const int wave = tid >> 6, lane = tid & 63;
  const int wr = wave >> 1, wc = wave & 1;
  // XCD-aware swizzle (m204, 768 = 8*96)
  const int lin = blockIdx.y * 12 + blockIdx.x;
  const int wg = (lin & 7) * 96 + (lin >> 3);
  const int m0 = (wg / 12) * 128, n0 = (wg % 12) * 64;

  f32x4 acc[4][2] = {};

#pragma unroll 1
  for (int k0 = 0; k0 < 768; k0 += 64) {
#pragma unroll
    for (int it = 0; it < 4; ++it) {
      int chunk = wave * 4 + it;
      int slot = chunk * 64 + lane;
      int row = slot >> 3, j = slot & 7;
      int kcol = k0 + ((j ^ (row & 7)) << 3);
      gld_lds16(A + (size_t)(m0 + row) * 768 + kcol, &As[chunk * 512]);
    }
#pragma unroll
    for (int it = 0; it < 2; ++it) {
      int chunk = wave * 2 + it;
      int slot = chunk * 64 + lane;
      int row = slot >> 3, j = slot & 7;
      int kcol = k0 + ((j ^ (row & 7)) << 3);
      gld_lds16(Bt + (size_t)(n0 + row) * 768 + kcol, &Bs[chunk * 512]);
    }
    __syncthreads();
#pragma unroll
    for (int kk = 0; kk < 2; ++kk) {
      bf16x8 af[4], bfr[2];
      int cbl = kk * 4 + (lane >> 4);
#pragma unroll
      for (int mi = 0; mi < 4; ++mi) {
        int row = wr * 64 + mi * 16 + (lane & 15);
        af[mi] = *(const bf16x8*)&As[(row * 8 + (cbl ^ (row & 7))) * 8];
      }
#pragma unroll
      for (int ni = 0; ni < 2; ++ni) {
        int row = wc * 32 + ni * 16 + (lane & 15);
        bfr[ni] = *(const bf16x8*)&Bs[(row * 8 + (cbl ^ (row & 7))) * 8];
      }
#pragma unroll
      for (int mi = 0; mi < 4; ++mi)
#pragma unroll
        for (int ni = 0; ni < 2; ++ni)
          acc[mi][ni] = __builtin_amdgcn_mfma_f32_16x16x32_bf16(af[mi], bfr[ni], acc[mi][ni], 0, 0, 0);
    }
    __syncthreads();
  }

#pragma unroll
  for (int ni = 0; ni < 2; ++ni) {
    int col = n0 + wc * 32 + ni * 16 + (lane & 15);
    float bi = bias[col];
#pragma unroll
    for (int mi = 0; mi < 4; ++mi) {
      int mt = m0 + wr * 64 + mi * 16 + ((lane >> 4) << 2);
#pragma unroll
      for (int r = 0; r < 4; ++r)
        out[(size_t)(mt + r) * CDIM + col] = acc[mi][ni][r] + bi;
    }
  }
}

extern "C" void kernel_launch(void* const* d_in, const int* in_sizes, int n_in,
                              void* d_out, int out_size, void* d_ws, size_t ws_size,
                              hipStream_t stream) {
  const float* x  = (const float*)d_in[0];
  const float* Wa = (const float*)d_in[1];
  const float* ba = (const float*)d_in[2];
  const float* Wp = (const float*)d_in[3];
  const float* bp = (const float*)d_in[4];

  char* ws = (char*)d_ws;
  unsigned short* xb  = (unsigned short*)(ws + OFF_XB);
  unsigned short* WaT = (unsigned short*)(ws + OFF_WAT);
  unsigned short* WpT = (unsigned short*)(ws + OFF_WPT);
  unsigned short* Qb  = (unsigned short*)(ws + OFF_Q);
  unsigned short* Kb  = (unsigned short*)(ws + OFF_K);
  unsigned short* Vtb = (unsigned short*)(ws + OFF_VT);
  unsigned short* Ob  = (unsigned short*)(ws + OFF_O);
  unsigned short* Opb = (unsigned short*)(ws + OFF_P);
  float*          Lpb = (float*)(ws + OFF_L);

  k_conv<<<3072, 256, 0, stream>>>(x, xb);
  k_transpose<<<dim3(36, 12), 256, 0, stream>>>(Wa, WaT, CDIM, 3 * CDIM);
  k_transpose<<<dim3(12, 12), 256, 0, stream>>>(Wp, WpT, CDIM, CDIM);
  k_qkv<<<dim3(18, 64), 256, 0, stream>>>(xb, WaT, ba, Qb, Kb, Vtb);
  k_attn<<<dim3(16, 24, 2), 256, 0, stream>>>(Qb, Kb, Vtb, Opb, Lpb);
  k_combine<<<3072, 256, 0, stream>>>(Opb, Lpb, Ob);
  k_proj<<<dim3(12, 64), 256, 0, stream>>>(Ob, WpT, bp, (float*)d_out);
}